// Round 1
// baseline (192.507 us; speedup 1.0000x reference)
//
#include <hip/hip_runtime.h>
#include <math.h>

// FNO 2D spectral conv, MI355X. B=8,H=256,W=256,CIN=COUT=32,M1=M2=16.
// R3: E-tables read via L1 (no LDS staging) in K1/K5; radix-2 fold moved to
// K1 staging (sxe/sxo); T relaid to [b][c][h][kw][2] so K2 streams
// contiguously; K2 at 1024 thr / 4-way h-split; K3+K4 fused (Y in LDS).

#define INV_HW (1.0f / 65536.0f)

// ------------------------------------------------------------- twiddle gen
// E1: [w<128][kwp<8] float4 (cos_e,-sin_e,cos_o,-sin_o), theta = 2pi*m/256
// U : [n<256] float2 (cos, sin) of +2pi*n/256
// E4: [w<128][q<8] float4 (sc_e*cos_e, sc_e*sin_e, sc_o*cos_o, sc_o*sin_o)
__global__ void k_tw(float* __restrict__ E1, float* __restrict__ U,
                     float* __restrict__ E4) {
  int t = blockIdx.x * blockDim.x + threadIdx.x;
  const float step = 6.28318530717958647692f / 256.0f;
  if (t < 1024) {
    int w = t >> 3, kwp = t & 7;
    int me = (2 * kwp * w) & 255, mo = ((2 * kwp + 1) * w) & 255;
    float se, ce, so, co;
    sincosf(step * (float)me, &se, &ce);
    sincosf(step * (float)mo, &so, &co);
    ((float4*)E1)[t] = make_float4(ce, -se, co, -so);
  } else if (t < 1280) {
    int n = t - 1024;
    float s, c;
    sincosf(step * (float)n, &s, &c);
    ((float2*)U)[n] = make_float2(c, s);
  } else if (t < 2304) {
    int i = t - 1280;
    int w = i >> 3, q = i & 7;
    int me = (2 * q * w) & 255, mo = ((2 * q + 1) * w) & 255;
    float se, ce, so, co;
    sincosf(step * (float)me, &se, &ce);
    sincosf(step * (float)mo, &so, &co);
    float sc_e = (q == 0) ? INV_HW : 2.0f * INV_HW;
    float sc_o = 2.0f * INV_HW;
    ((float4*)E4)[i] = make_float4(sc_e * ce, sc_e * se, sc_o * co, sc_o * so);
  }
}

// ------------------------------------------------- K1: w-DFT  x -> T
// block=(b,h) 2048. T layout [b][c][h][kw][2]. Radix-2 fold at staging:
// sxe/sxo [c][132] (b128-aligned, conflict-free reads). E1 read from L1.
__global__ __launch_bounds__(256) void k_wdft(const float* __restrict__ x,
                                              const float* __restrict__ E1,
                                              float* __restrict__ T) {
  __shared__ __align__(16) float sxe[32 * 132];  // 16.9 KB
  __shared__ __align__(16) float sxo[32 * 132];  // 16.9 KB
  int bh = blockIdx.x, t = threadIdx.x;
  const float4* src = (const float4*)(x + (size_t)bh * 8192);
#pragma unroll
  for (int i = 0; i < 4; ++i) {
    int j = t + 256 * i;                 // j < 1024 -> w < 128
    float4 a = src[j];                   // w
    float4 b = src[j + 1024];            // w + 128
    int w = j >> 3, c0 = (j & 7) * 4;
    sxe[(c0 + 0) * 132 + w] = a.x + b.x;
    sxe[(c0 + 1) * 132 + w] = a.y + b.y;
    sxe[(c0 + 2) * 132 + w] = a.z + b.z;
    sxe[(c0 + 3) * 132 + w] = a.w + b.w;
    sxo[(c0 + 0) * 132 + w] = a.x - b.x;
    sxo[(c0 + 1) * 132 + w] = a.y - b.y;
    sxo[(c0 + 2) * 132 + w] = a.z - b.z;
    sxo[(c0 + 3) * 132 + w] = a.w - b.w;
  }
  __syncthreads();
  int c = t >> 3, kwp = t & 7;
  const float* xe = sxe + c * 132;
  const float* xo = sxo + c * 132;
  const float4* eb = ((const float4*)E1) + kwp;  // L1-resident 16 KB table
  float ar = 0, ai = 0, br = 0, bi = 0;
#pragma unroll 4
  for (int j = 0; j < 32; ++j) {
    float4 ye = *(const float4*)(xe + 4 * j);
    float4 yo = *(const float4*)(xo + 4 * j);
    float4 e0 = eb[(4 * j + 0) * 8];
    float4 e1 = eb[(4 * j + 1) * 8];
    float4 e2 = eb[(4 * j + 2) * 8];
    float4 e3 = eb[(4 * j + 3) * 8];
    ar += ye.x * e0.x; ai += ye.x * e0.y; br += yo.x * e0.z; bi += yo.x * e0.w;
    ar += ye.y * e1.x; ai += ye.y * e1.y; br += yo.y * e1.z; bi += yo.y * e1.w;
    ar += ye.z * e2.x; ai += ye.z * e2.y; br += yo.z * e2.z; bi += yo.z * e2.w;
    ar += ye.w * e3.x; ai += ye.w * e3.y; br += yo.w * e3.z; bi += yo.w * e3.w;
  }
  int b = bh >> 8, h = bh & 255;
  ((float4*)(T + ((size_t)(b * 32 + c) * 256 + h) * 32))[kwp] =
      make_float4(ar, ai, br, bi);
}

// ------------------------------------------------- K2: h-DFT  T -> X
// block=(b,c) 256 x 1024 thr. T now contiguous per (b,c): straight copy.
// 4-way h-split partials + LDS reduce. 16 waves/CU.
__global__ __launch_bounds__(1024) void k_hdft(const float* __restrict__ T,
                                               const float* __restrict__ U,
                                               float* __restrict__ X) {
  __shared__ __align__(16) float sT[8192];  // [h][kw][2] 32 KB
  __shared__ float2 sU[256];
  __shared__ float4 sRed[768];              // 12 KB
  int t = threadIdx.x;
  const float4* src = (const float4*)(T + (size_t)blockIdx.x * 8192);
  float4* dT = (float4*)sT;
  dT[t] = src[t];
  dT[t + 1024] = src[t + 1024];
  if (t < 256) sU[t] = ((const float2*)U)[t];
  __syncthreads();
  int kw = t & 15, kh = (t >> 4) & 15, s = t >> 8;  // s = h-quarter
  float sg = (kh & 1) ? -1.f : 1.f;  // (-1)^kha, kha parity == kh parity
  int st1 = kh, st2 = (kh + 240) & 255;
  int h0 = s * 32;
  int ph1 = (st1 * h0) & 255;
  int ph2 = (st2 * h0) & 255;
  float x0r = 0, x0i = 0, x1r = 0, x1i = 0;
#pragma unroll 4
  for (int hh = 0; hh < 32; ++hh) {
    int h = h0 + hh;
    float2 t0 = *(const float2*)(sT + h * 32 + kw * 2);
    float2 t1 = *(const float2*)(sT + (h + 128) * 32 + kw * 2);
    float tpx = fmaf(sg, t1.x, t0.x);
    float tpy = fmaf(sg, t1.y, t0.y);
    float2 e1 = sU[ph1];
    float2 e2 = sU[ph2];
    x0r += tpx * e1.x + tpy * e1.y;
    x0i += tpy * e1.x - tpx * e1.y;
    x1r += tpx * e2.x + tpy * e2.y;
    x1i += tpy * e2.x - tpx * e2.y;
    ph1 = (ph1 + st1) & 255;
    ph2 = (ph2 + st2) & 255;
  }
  if (s > 0) sRed[(s - 1) * 256 + (t & 255)] = make_float4(x0r, x0i, x1r, x1i);
  __syncthreads();
  if (s == 0) {
#pragma unroll
    for (int k = 0; k < 3; ++k) {
      float4 p = sRed[k * 256 + t];
      x0r += p.x; x0i += p.y; x1r += p.z; x1i += p.w;
    }
    float2* Xb = (float2*)(X + (size_t)blockIdx.x * 1024);
    Xb[kh * 16 + kw] = make_float2(x0r, x0i);          // kha = kh
    Xb[(kh + 16) * 16 + kw] = make_float2(x1r, x1i);   // kha = kh+240
  }
}

// ------------------------------------------------- K34: mix + h-IDFT  X -> G
// grid (b,o) = 256, 512 thr. Phase A: Y[b][o][kh][kw] into LDS (4 KB).
// Phase B: h-IDFT (radix-2 over h) straight to G. Kills Y round-trip.
__global__ __launch_bounds__(512) void k_mixidft(const float* __restrict__ X,
                                                 const float* __restrict__ wr,
                                                 const float* __restrict__ wi,
                                                 const float* __restrict__ U,
                                                 float* __restrict__ G) {
  __shared__ __align__(16) float2 sY[512];  // [row32][kw16] 4 KB
  __shared__ float2 sU[256];
  int b = blockIdx.x >> 5, o = blockIdx.x & 31;
  int t = threadIdx.x;
  if (t < 256) sU[t] = ((const float2*)U)[t];
  {  // phase A: channel mix, one (row,kw) per thread
    int kw = t & 15, row = t >> 4;          // row 0..31
    int blk = row >> 4, khl = row & 15;
    const float* wr0 =
        wr + (size_t)blk * 262144 + (size_t)o * 256 + khl * 16 + kw;
    const float* wi0 =
        wi + (size_t)blk * 262144 + (size_t)o * 256 + khl * 16 + kw;
    const float* Xb = X + (size_t)b * 32768 + row * 32 + kw * 2;
    float yr = 0, yi = 0;
#pragma unroll 4
    for (int i = 0; i < 32; ++i) {
      float2 xv = *(const float2*)(Xb + i * 1024);
      float a = wr0[i * 8192], bb = wi0[i * 8192];
      yr += xv.x * a - xv.y * bb;
      yi += xv.x * bb + xv.y * a;
    }
    sY[row * 16 + kw] = make_float2(yr, yi);
  }
  __syncthreads();
  // phase B: h-IDFT; even rows -> even kha (se), odd rows -> odd kha (so)
  const float4* sY4 = (const float4*)sY;
  int q = t & 7, hr = t >> 3;  // hr 0..63
#pragma unroll
  for (int hb = 0; hb < 2; ++hb) {
    int h = hr + hb * 64;  // 0..127; mirror h+128 via se-so
    float se0r = 0, se0i = 0, se1r = 0, se1i = 0;
    float so0r = 0, so0i = 0, so1r = 0, so1i = 0;
#pragma unroll 4
    for (int kh2 = 0; kh2 < 16; ++kh2) {
      int khe = 2 * kh2, kho = khe + 1;
      int khae = khe < 16 ? khe : khe + 224;
      int khao = kho < 16 ? kho : kho + 224;
      float2 ee = sU[(khae * h) & 255];
      float2 eo = sU[(khao * h) & 255];
      float4 yE = sY4[khe * 8 + q];
      float4 yO = sY4[kho * 8 + q];
      se0r += yE.x * ee.x - yE.y * ee.y;
      se0i += yE.x * ee.y + yE.y * ee.x;
      se1r += yE.z * ee.x - yE.w * ee.y;
      se1i += yE.z * ee.y + yE.w * ee.x;
      so0r += yO.x * eo.x - yO.y * eo.y;
      so0i += yO.x * eo.y + yO.y * eo.x;
      so1r += yO.z * eo.x - yO.w * eo.y;
      so1i += yO.z * eo.y + yO.w * eo.x;
    }
    float* g0 = G + (((size_t)b * 256 + h) * 32 + o) * 32 + 4 * q;
    float* g1 = G + (((size_t)b * 256 + h + 128) * 32 + o) * 32 + 4 * q;
    *(float4*)g0 =
        make_float4(se0r + so0r, se0i + so0i, se1r + so1r, se1i + so1i);
    *(float4*)g1 =
        make_float4(se0r - so0r, se0i - so0i, se1r - so1r, se1i - so1i);
  }
}

// ------------------------------------------------- K5: w-IDFT (c2r) G -> out
// E4 read from L1 (no LDS staging): 4.2 KB LDS -> 8 blocks/CU, 32 waves.
__global__ __launch_bounds__(256) void k_widft(const float* __restrict__ G,
                                               const float* __restrict__ E4,
                                               float* __restrict__ out) {
  __shared__ float sG[32 * 33];
  int bh = blockIdx.x, t = threadIdx.x;
  {
    float4 v = ((const float4*)(G + (size_t)bh * 1024))[t];
    int o = t >> 3, p = t & 7;
    float* d = sG + o * 33 + p * 4;
    d[0] = v.x; d[1] = v.y; d[2] = v.z; d[3] = v.w;
  }
  __syncthreads();
  int o = t & 31, wb = t >> 5;
  float g[32];
#pragma unroll
  for (int k = 0; k < 32; ++k) g[k] = sG[o * 33 + k];
  const float4* e4g = (const float4*)E4;  // L1-resident 16 KB table
  float* ob = out + (size_t)bh * 8192 + o;
#pragma unroll 2
  for (int j = 0; j < 16; ++j) {
    int w = wb * 16 + j;
    float se = 0.f, so = 0.f;
#pragma unroll
    for (int q = 0; q < 8; ++q) {
      float4 e = e4g[w * 8 + q];
      se += g[4 * q] * e.x - g[4 * q + 1] * e.y;
      so += g[4 * q + 2] * e.z - g[4 * q + 3] * e.w;
    }
    ob[(size_t)w * 32] = se + so;
    ob[(size_t)(w + 128) * 32] = se - so;
  }
}

extern "C" void kernel_launch(void* const* d_in, const int* in_sizes, int n_in,
                              void* d_out, int out_size, void* d_ws,
                              size_t ws_size, hipStream_t stream) {
  const float* x = (const float*)d_in[0];   // [8,256,256,32]
  const float* wr = (const float*)d_in[1];  // [2,32,32,16,16]
  const float* wi = (const float*)d_in[2];
  float* out = (float*)d_out;               // [8,256,256,32]
  float* ws = (float*)d_ws;

  float* E1 = ws;            // 4096 f
  float* U  = ws + 4096;     // 512 f
  float* E4 = ws + 4608;     // 4096 f
  float* T  = ws + 8704;     // 2097152 f  [b][c][h][kw][2]
  float* X  = ws + 2105856;  // 262144 f   [b*32+c][row][kw][2]
  float* G  = T;             // reuse (T dead after K2)

  k_tw<<<9, 256, 0, stream>>>(E1, U, E4);
  k_wdft<<<2048, 256, 0, stream>>>(x, E1, T);
  k_hdft<<<256, 1024, 0, stream>>>(T, U, X);
  k_mixidft<<<256, 512, 0, stream>>>(X, wr, wi, U, G);
  k_widft<<<2048, 256, 0, stream>>>(G, E4, out);
}

// Round 2
// 157.796 us; speedup vs baseline: 1.2200x; 1.2200x over previous
//
#include <hip/hip_runtime.h>
#include <math.h>

// FNO 2D spectral conv, MI355X. B=8,H=256,W=256,CIN=COUT=32,M1=M2=16.
// R4: K1 = LDS-staged E1 (revert R3's global-E1 regression) + radix-2 fold
// at staging (sxe/sxo) + T layout [b][c][h][kw][2]. K2 = contiguous stream,
// 1024 thr. K34 fused (Y in LDS). K5 = LDS-staged E4 (revert).

#define INV_HW (1.0f / 65536.0f)

// ------------------------------------------------------------- twiddle gen
// E1: [w<128][kwp<8] float4 (cos_e,-sin_e,cos_o,-sin_o), theta = 2pi*m/256
// U : [n<256] float2 (cos, sin) of +2pi*n/256
// E4: [w<128][q<8] float4 (sc_e*cos_e, sc_e*sin_e, sc_o*cos_o, sc_o*sin_o)
__global__ void k_tw(float* __restrict__ E1, float* __restrict__ U,
                     float* __restrict__ E4) {
  int t = blockIdx.x * blockDim.x + threadIdx.x;
  const float step = 6.28318530717958647692f / 256.0f;
  if (t < 1024) {
    int w = t >> 3, kwp = t & 7;
    int me = (2 * kwp * w) & 255, mo = ((2 * kwp + 1) * w) & 255;
    float se, ce, so, co;
    sincosf(step * (float)me, &se, &ce);
    sincosf(step * (float)mo, &so, &co);
    ((float4*)E1)[t] = make_float4(ce, -se, co, -so);
  } else if (t < 1280) {
    int n = t - 1024;
    float s, c;
    sincosf(step * (float)n, &s, &c);
    ((float2*)U)[n] = make_float2(c, s);
  } else if (t < 2304) {
    int i = t - 1280;
    int w = i >> 3, q = i & 7;
    int me = (2 * q * w) & 255, mo = ((2 * q + 1) * w) & 255;
    float se, ce, so, co;
    sincosf(step * (float)me, &se, &ce);
    sincosf(step * (float)mo, &so, &co);
    float sc_e = (q == 0) ? INV_HW : 2.0f * INV_HW;
    float sc_o = 2.0f * INV_HW;
    ((float4*)E4)[i] = make_float4(sc_e * ce, sc_e * se, sc_o * co, sc_o * so);
  }
}

// ------------------------------------------------- K1: w-DFT  x -> T
// block=(b,h) 2048. Radix-2 fold at staging into sxe/sxo [c][132].
// E1 staged in LDS (16 KB). T layout [b][c][h][kw][2].
__global__ __launch_bounds__(256) void k_wdft(const float* __restrict__ x,
                                              const float* __restrict__ E1,
                                              float* __restrict__ T) {
  __shared__ __align__(16) float sxe[32 * 132];  // 16.9 KB
  __shared__ __align__(16) float sxo[32 * 132];  // 16.9 KB
  __shared__ float4 sE[1024];                    // 16 KB
  int bh = blockIdx.x, t = threadIdx.x;
  const float4* e1g = (const float4*)E1;
#pragma unroll
  for (int i = 0; i < 4; ++i) sE[t + 256 * i] = e1g[t + 256 * i];
  const float4* src = (const float4*)(x + (size_t)bh * 8192);
#pragma unroll
  for (int i = 0; i < 4; ++i) {
    int j = t + 256 * i;                 // j < 1024 -> w < 128
    float4 a = src[j];                   // w
    float4 b = src[j + 1024];            // w + 128
    int w = j >> 3, c0 = (j & 7) * 4;
    sxe[(c0 + 0) * 132 + w] = a.x + b.x;
    sxe[(c0 + 1) * 132 + w] = a.y + b.y;
    sxe[(c0 + 2) * 132 + w] = a.z + b.z;
    sxe[(c0 + 3) * 132 + w] = a.w + b.w;
    sxo[(c0 + 0) * 132 + w] = a.x - b.x;
    sxo[(c0 + 1) * 132 + w] = a.y - b.y;
    sxo[(c0 + 2) * 132 + w] = a.z - b.z;
    sxo[(c0 + 3) * 132 + w] = a.w - b.w;
  }
  __syncthreads();
  int c = t >> 3, kwp = t & 7;
  const float* xe = sxe + c * 132;
  const float* xo = sxo + c * 132;
  const float4* eb = sE + kwp;
  float ar = 0, ai = 0, br = 0, bi = 0;
#pragma unroll 4
  for (int j = 0; j < 32; ++j) {
    float4 ye = *(const float4*)(xe + 4 * j);
    float4 yo = *(const float4*)(xo + 4 * j);
    float4 e0 = eb[(4 * j + 0) * 8];
    float4 e1 = eb[(4 * j + 1) * 8];
    float4 e2 = eb[(4 * j + 2) * 8];
    float4 e3 = eb[(4 * j + 3) * 8];
    ar += ye.x * e0.x; ai += ye.x * e0.y; br += yo.x * e0.z; bi += yo.x * e0.w;
    ar += ye.y * e1.x; ai += ye.y * e1.y; br += yo.y * e1.z; bi += yo.y * e1.w;
    ar += ye.z * e2.x; ai += ye.z * e2.y; br += yo.z * e2.z; bi += yo.z * e2.w;
    ar += ye.w * e3.x; ai += ye.w * e3.y; br += yo.w * e3.z; bi += yo.w * e3.w;
  }
  int b = bh >> 8, h = bh & 255;
  ((float4*)(T + ((size_t)(b * 32 + c) * 256 + h) * 32))[kwp] =
      make_float4(ar, ai, br, bi);
}

// ------------------------------------------------- K2: h-DFT  T -> X
// block=(b,c) 256 x 1024 thr. T contiguous per (b,c): straight copy.
// 4-way h-split partials + LDS reduce.
__global__ __launch_bounds__(1024) void k_hdft(const float* __restrict__ T,
                                               const float* __restrict__ U,
                                               float* __restrict__ X) {
  __shared__ __align__(16) float sT[8192];  // [h][kw][2] 32 KB
  __shared__ float2 sU[256];
  __shared__ float4 sRed[768];              // 12 KB
  int t = threadIdx.x;
  const float4* src = (const float4*)(T + (size_t)blockIdx.x * 8192);
  float4* dT = (float4*)sT;
  dT[t] = src[t];
  dT[t + 1024] = src[t + 1024];
  if (t < 256) sU[t] = ((const float2*)U)[t];
  __syncthreads();
  int kw = t & 15, kh = (t >> 4) & 15, s = t >> 8;  // s = h-quarter
  float sg = (kh & 1) ? -1.f : 1.f;  // (-1)^kha, kha parity == kh parity
  int st1 = kh, st2 = (kh + 240) & 255;
  int h0 = s * 32;
  int ph1 = (st1 * h0) & 255;
  int ph2 = (st2 * h0) & 255;
  float x0r = 0, x0i = 0, x1r = 0, x1i = 0;
#pragma unroll 4
  for (int hh = 0; hh < 32; ++hh) {
    int h = h0 + hh;
    float2 t0 = *(const float2*)(sT + h * 32 + kw * 2);
    float2 t1 = *(const float2*)(sT + (h + 128) * 32 + kw * 2);
    float tpx = fmaf(sg, t1.x, t0.x);
    float tpy = fmaf(sg, t1.y, t0.y);
    float2 e1 = sU[ph1];
    float2 e2 = sU[ph2];
    x0r += tpx * e1.x + tpy * e1.y;
    x0i += tpy * e1.x - tpx * e1.y;
    x1r += tpx * e2.x + tpy * e2.y;
    x1i += tpy * e2.x - tpx * e2.y;
    ph1 = (ph1 + st1) & 255;
    ph2 = (ph2 + st2) & 255;
  }
  if (s > 0) sRed[(s - 1) * 256 + (t & 255)] = make_float4(x0r, x0i, x1r, x1i);
  __syncthreads();
  if (s == 0) {
#pragma unroll
    for (int k = 0; k < 3; ++k) {
      float4 p = sRed[k * 256 + t];
      x0r += p.x; x0i += p.y; x1r += p.z; x1i += p.w;
    }
    float2* Xb = (float2*)(X + (size_t)blockIdx.x * 1024);
    Xb[kh * 16 + kw] = make_float2(x0r, x0i);          // kha = kh
    Xb[(kh + 16) * 16 + kw] = make_float2(x1r, x1i);   // kha = kh+240
  }
}

// ------------------------------------------------- K34: mix + h-IDFT  X -> G
// grid (b,o) = 256, 512 thr. Phase A: Y[b][o][kh][kw] into LDS (4 KB).
// Phase B: h-IDFT (radix-2 over h) straight to G.
__global__ __launch_bounds__(512) void k_mixidft(const float* __restrict__ X,
                                                 const float* __restrict__ wr,
                                                 const float* __restrict__ wi,
                                                 const float* __restrict__ U,
                                                 float* __restrict__ G) {
  __shared__ __align__(16) float2 sY[512];  // [row32][kw16] 4 KB
  __shared__ float2 sU[256];
  int b = blockIdx.x >> 5, o = blockIdx.x & 31;
  int t = threadIdx.x;
  if (t < 256) sU[t] = ((const float2*)U)[t];
  {  // phase A: channel mix, one (row,kw) per thread
    int kw = t & 15, row = t >> 4;          // row 0..31
    int blk = row >> 4, khl = row & 15;
    const float* wr0 =
        wr + (size_t)blk * 262144 + (size_t)o * 256 + khl * 16 + kw;
    const float* wi0 =
        wi + (size_t)blk * 262144 + (size_t)o * 256 + khl * 16 + kw;
    const float* Xb = X + (size_t)b * 32768 + row * 32 + kw * 2;
    float yr = 0, yi = 0;
#pragma unroll 4
    for (int i = 0; i < 32; ++i) {
      float2 xv = *(const float2*)(Xb + i * 1024);
      float a = wr0[i * 8192], bb = wi0[i * 8192];
      yr += xv.x * a - xv.y * bb;
      yi += xv.x * bb + xv.y * a;
    }
    sY[row * 16 + kw] = make_float2(yr, yi);
  }
  __syncthreads();
  // phase B: h-IDFT; even rows -> even kha (se), odd rows -> odd kha (so)
  const float4* sY4 = (const float4*)sY;
  int q = t & 7, hr = t >> 3;  // hr 0..63
#pragma unroll
  for (int hb = 0; hb < 2; ++hb) {
    int h = hr + hb * 64;  // 0..127; mirror h+128 via se-so
    float se0r = 0, se0i = 0, se1r = 0, se1i = 0;
    float so0r = 0, so0i = 0, so1r = 0, so1i = 0;
#pragma unroll 4
    for (int kh2 = 0; kh2 < 16; ++kh2) {
      int khe = 2 * kh2, kho = khe + 1;
      int khae = khe < 16 ? khe : khe + 224;
      int khao = kho < 16 ? kho : kho + 224;
      float2 ee = sU[(khae * h) & 255];
      float2 eo = sU[(khao * h) & 255];
      float4 yE = sY4[khe * 8 + q];
      float4 yO = sY4[kho * 8 + q];
      se0r += yE.x * ee.x - yE.y * ee.y;
      se0i += yE.x * ee.y + yE.y * ee.x;
      se1r += yE.z * ee.x - yE.w * ee.y;
      se1i += yE.z * ee.y + yE.w * ee.x;
      so0r += yO.x * eo.x - yO.y * eo.y;
      so0i += yO.x * eo.y + yO.y * eo.x;
      so1r += yO.z * eo.x - yO.w * eo.y;
      so1i += yO.z * eo.y + yO.w * eo.x;
    }
    float* g0 = G + (((size_t)b * 256 + h) * 32 + o) * 32 + 4 * q;
    float* g1 = G + (((size_t)b * 256 + h + 128) * 32 + o) * 32 + 4 * q;
    *(float4*)g0 =
        make_float4(se0r + so0r, se0i + so0i, se1r + so1r, se1i + so1i);
    *(float4*)g1 =
        make_float4(se0r - so0r, se0i - so0i, se1r - so1r, se1i - so1i);
  }
}

// ------------------------------------------------- K5: w-IDFT (c2r) G -> out
// E4 staged in LDS (16 KB).
__global__ __launch_bounds__(256) void k_widft(const float* __restrict__ G,
                                               const float* __restrict__ E4,
                                               float* __restrict__ out) {
  __shared__ float sG[32 * 33];
  __shared__ float4 sE4[1024];  // 16 KB
  int bh = blockIdx.x, t = threadIdx.x;
  const float4* e4g = (const float4*)E4;
#pragma unroll
  for (int i = 0; i < 4; ++i) sE4[t + 256 * i] = e4g[t + 256 * i];
  {
    float4 v = ((const float4*)(G + (size_t)bh * 1024))[t];
    int o = t >> 3, p = t & 7;
    float* d = sG + o * 33 + p * 4;
    d[0] = v.x; d[1] = v.y; d[2] = v.z; d[3] = v.w;
  }
  __syncthreads();
  int o = t & 31, wb = t >> 5;
  float g[32];
#pragma unroll
  for (int k = 0; k < 32; ++k) g[k] = sG[o * 33 + k];
  float* ob = out + (size_t)bh * 8192 + o;
#pragma unroll 2
  for (int j = 0; j < 16; ++j) {
    int w = wb * 16 + j;
    float se = 0.f, so = 0.f;
#pragma unroll
    for (int q = 0; q < 8; ++q) {
      float4 e = sE4[w * 8 + q];
      se += g[4 * q] * e.x - g[4 * q + 1] * e.y;
      so += g[4 * q + 2] * e.z - g[4 * q + 3] * e.w;
    }
    ob[(size_t)w * 32] = se + so;
    ob[(size_t)(w + 128) * 32] = se - so;
  }
}

extern "C" void kernel_launch(void* const* d_in, const int* in_sizes, int n_in,
                              void* d_out, int out_size, void* d_ws,
                              size_t ws_size, hipStream_t stream) {
  const float* x = (const float*)d_in[0];   // [8,256,256,32]
  const float* wr = (const float*)d_in[1];  // [2,32,32,16,16]
  const float* wi = (const float*)d_in[2];
  float* out = (float*)d_out;               // [8,256,256,32]
  float* ws = (float*)d_ws;

  float* E1 = ws;            // 4096 f
  float* U  = ws + 4096;     // 512 f
  float* E4 = ws + 4608;     // 4096 f
  float* T  = ws + 8704;     // 2097152 f  [b][c][h][kw][2]
  float* X  = ws + 2105856;  // 262144 f   [b*32+c][row][kw][2]
  float* G  = T;             // reuse (T dead after K2)

  k_tw<<<9, 256, 0, stream>>>(E1, U, E4);
  k_wdft<<<2048, 256, 0, stream>>>(x, E1, T);
  k_hdft<<<256, 1024, 0, stream>>>(T, U, X);
  k_mixidft<<<256, 512, 0, stream>>>(X, wr, wi, U, G);
  k_widft<<<2048, 256, 0, stream>>>(G, E4, out);
}

// Round 3
// 156.189 us; speedup vs baseline: 1.2325x; 1.0103x over previous
//
#include <hip/hip_runtime.h>
#include <math.h>

// FNO 2D spectral conv, MI355X. B=8,H=256,W=256,CIN=COUT=32,M1=M2=16.
// R5: k_tw eliminated (inline twiddle gen in load shadow, all kernels).
// K1: 512 thr / 2 h-rows per block, half E-table (w->w+64 symmetry, exact
// +-1/+-i fixup at epilogue), 128 ds_read_b128/thread (was 192), pad 136
// (2-way = free write conflicts), 77.8 KB LDS -> 2 blocks/CU (16 waves).
// K2/K34: inline sU gen. K5: inline E4 gen (kills 33 MB L2 re-read).

#define INV_HW (1.0f / 65536.0f)
#define STEP256 (6.28318530717958647692f / 256.0f)

// ------------------------------------------------- K1: w-DFT  x -> T
// grid 1024 = (b, h-pair). T layout [b][c][h][kw][2].
__global__ __launch_bounds__(512) void k_wdft(const float* __restrict__ x,
                                              float* __restrict__ T) {
  __shared__ __align__(16) float sxe[2][32 * 136];  // 34.0 KB
  __shared__ __align__(16) float sxo[2][32 * 136];  // 34.0 KB
  __shared__ __align__(16) float4 sE[512];          // [w<64][kwp] 8 KB
  int t = threadIdx.x;
  int b = blockIdx.x >> 7, h0 = (blockIdx.x & 127) << 1;
  int sub = t >> 8, tsub = t & 255;
  const float4* src =
      (const float4*)(x + ((size_t)(b * 256 + h0 + sub)) * 8192);
  float4 av[4], bv[4];
#pragma unroll
  for (int i = 0; i < 4; ++i) {
    av[i] = src[tsub + 256 * i];
    bv[i] = src[tsub + 256 * i + 1024];
  }
  {  // twiddle gen (TRANS pipe) hidden under the global loads
    int w = t >> 3, kwp = t & 7;
    int me = (2 * kwp * w) & 255, mo = ((2 * kwp + 1) * w) & 255;
    float se, ce, so, co;
    sincosf(STEP256 * (float)me, &se, &ce);
    sincosf(STEP256 * (float)mo, &so, &co);
    sE[t] = make_float4(ce, -se, co, -so);
  }
  float* pe = &sxe[sub][0];
  float* po = &sxo[sub][0];
#pragma unroll
  for (int i = 0; i < 4; ++i) {
    int j = tsub + 256 * i;  // j < 1024 -> w < 128
    int w = j >> 3, c0 = (j & 7) * 4;
    float4 a = av[i], bb = bv[i];
    pe[(c0 + 0) * 136 + w] = a.x + bb.x;
    pe[(c0 + 1) * 136 + w] = a.y + bb.y;
    pe[(c0 + 2) * 136 + w] = a.z + bb.z;
    pe[(c0 + 3) * 136 + w] = a.w + bb.w;
    po[(c0 + 0) * 136 + w] = a.x - bb.x;
    po[(c0 + 1) * 136 + w] = a.y - bb.y;
    po[(c0 + 2) * 136 + w] = a.z - bb.z;
    po[(c0 + 3) * 136 + w] = a.w - bb.w;
  }
  __syncthreads();
  int c = (t >> 3) & 31, kwp = t & 7;
  const float* xe = pe + c * 136;
  const float* xo = po + c * 136;
  const float4* eb = sE + kwp;
  float arl = 0, ail = 0, brl = 0, bil = 0;
  float arh = 0, aih = 0, brh = 0, bih = 0;
#pragma unroll 4
  for (int j = 0; j < 16; ++j) {
    float4 yel = *(const float4*)(xe + 4 * j);
    float4 yeh = *(const float4*)(xe + 64 + 4 * j);
    float4 yol = *(const float4*)(xo + 4 * j);
    float4 yoh = *(const float4*)(xo + 64 + 4 * j);
    float4 e0 = eb[(4 * j + 0) * 8];
    float4 e1 = eb[(4 * j + 1) * 8];
    float4 e2 = eb[(4 * j + 2) * 8];
    float4 e3 = eb[(4 * j + 3) * 8];
    arl += yel.x * e0.x; ail += yel.x * e0.y;
    brl += yol.x * e0.z; bil += yol.x * e0.w;
    arh += yeh.x * e0.x; aih += yeh.x * e0.y;
    brh += yoh.x * e0.z; bih += yoh.x * e0.w;
    arl += yel.y * e1.x; ail += yel.y * e1.y;
    brl += yol.y * e1.z; bil += yol.y * e1.w;
    arh += yeh.y * e1.x; aih += yeh.y * e1.y;
    brh += yoh.y * e1.z; bih += yoh.y * e1.w;
    arl += yel.z * e2.x; ail += yel.z * e2.y;
    brl += yol.z * e2.z; bil += yol.z * e2.w;
    arh += yeh.z * e2.x; aih += yeh.z * e2.y;
    brh += yoh.z * e2.z; bih += yoh.z * e2.w;
    arl += yel.w * e3.x; ail += yel.w * e3.y;
    brl += yol.w * e3.z; bil += yol.w * e3.w;
    arh += yeh.w * e3.x; aih += yeh.w * e3.y;
    brh += yoh.w * e3.z; bih += yoh.w * e3.w;
  }
  // T[2k]   = A_lo + (-1)^k A_hi
  // T[2k+1] = B_lo + (-1)^k (-i) B_hi
  float sgn = (kwp & 1) ? -1.f : 1.f;
  float ar = fmaf(sgn, arh, arl);
  float ai = fmaf(sgn, aih, ail);
  float br = fmaf(sgn, bih, brl);
  float bi = fmaf(-sgn, brh, bil);
  int h = h0 + sub;
  ((float4*)(T + ((size_t)(b * 32 + c) * 256 + h) * 32))[kwp] =
      make_float4(ar, ai, br, bi);
}

// ------------------------------------------------- K2: h-DFT  T -> X
// block=(b,c) 256 x 1024 thr. Contiguous T stream; 4-way h-split + reduce.
__global__ __launch_bounds__(1024) void k_hdft(const float* __restrict__ T,
                                               float* __restrict__ X) {
  __shared__ __align__(16) float sT[8192];  // [h][kw][2] 32 KB
  __shared__ float2 sU[256];
  __shared__ float4 sRed[768];              // 12 KB
  int t = threadIdx.x;
  const float4* src = (const float4*)(T + (size_t)blockIdx.x * 8192);
  float4* dT = (float4*)sT;
  dT[t] = src[t];
  dT[t + 1024] = src[t + 1024];
  if (t < 256) {
    float s, c;
    sincosf(STEP256 * (float)t, &s, &c);
    sU[t] = make_float2(c, s);
  }
  __syncthreads();
  int kw = t & 15, kh = (t >> 4) & 15, s = t >> 8;  // s = h-quarter
  float sg = (kh & 1) ? -1.f : 1.f;  // (-1)^kha, kha parity == kh parity
  int st1 = kh, st2 = (kh + 240) & 255;
  int h0 = s * 32;
  int ph1 = (st1 * h0) & 255;
  int ph2 = (st2 * h0) & 255;
  float x0r = 0, x0i = 0, x1r = 0, x1i = 0;
#pragma unroll 4
  for (int hh = 0; hh < 32; ++hh) {
    int h = h0 + hh;
    float2 t0 = *(const float2*)(sT + h * 32 + kw * 2);
    float2 t1 = *(const float2*)(sT + (h + 128) * 32 + kw * 2);
    float tpx = fmaf(sg, t1.x, t0.x);
    float tpy = fmaf(sg, t1.y, t0.y);
    float2 e1 = sU[ph1];
    float2 e2 = sU[ph2];
    x0r += tpx * e1.x + tpy * e1.y;
    x0i += tpy * e1.x - tpx * e1.y;
    x1r += tpx * e2.x + tpy * e2.y;
    x1i += tpy * e2.x - tpx * e2.y;
    ph1 = (ph1 + st1) & 255;
    ph2 = (ph2 + st2) & 255;
  }
  if (s > 0) sRed[(s - 1) * 256 + (t & 255)] = make_float4(x0r, x0i, x1r, x1i);
  __syncthreads();
  if (s == 0) {
#pragma unroll
    for (int k = 0; k < 3; ++k) {
      float4 p = sRed[k * 256 + t];
      x0r += p.x; x0i += p.y; x1r += p.z; x1i += p.w;
    }
    float2* Xb = (float2*)(X + (size_t)blockIdx.x * 1024);
    Xb[kh * 16 + kw] = make_float2(x0r, x0i);          // kha = kh
    Xb[(kh + 16) * 16 + kw] = make_float2(x1r, x1i);   // kha = kh+240
  }
}

// ------------------------------------------------- K34: mix + h-IDFT  X -> G
// grid (b,o) = 256, 512 thr. Phase A: Y into LDS (4 KB). Phase B: h-IDFT.
__global__ __launch_bounds__(512) void k_mixidft(const float* __restrict__ X,
                                                 const float* __restrict__ wr,
                                                 const float* __restrict__ wi,
                                                 float* __restrict__ G) {
  __shared__ __align__(16) float2 sY[512];  // [row32][kw16] 4 KB
  __shared__ float2 sU[256];
  int b = blockIdx.x >> 5, o = blockIdx.x & 31;
  int t = threadIdx.x;
  if (t < 256) {
    float s, c;
    sincosf(STEP256 * (float)t, &s, &c);
    sU[t] = make_float2(c, s);
  }
  {  // phase A: channel mix, one (row,kw) per thread
    int kw = t & 15, row = t >> 4;          // row 0..31
    int blk = row >> 4, khl = row & 15;
    const float* wr0 =
        wr + (size_t)blk * 262144 + (size_t)o * 256 + khl * 16 + kw;
    const float* wi0 =
        wi + (size_t)blk * 262144 + (size_t)o * 256 + khl * 16 + kw;
    const float* Xb = X + (size_t)b * 32768 + row * 32 + kw * 2;
    float yr = 0, yi = 0;
#pragma unroll 4
    for (int i = 0; i < 32; ++i) {
      float2 xv = *(const float2*)(Xb + i * 1024);
      float a = wr0[i * 8192], bb = wi0[i * 8192];
      yr += xv.x * a - xv.y * bb;
      yi += xv.x * bb + xv.y * a;
    }
    sY[row * 16 + kw] = make_float2(yr, yi);
  }
  __syncthreads();
  // phase B: h-IDFT; even rows -> even kha (se), odd rows -> odd kha (so)
  const float4* sY4 = (const float4*)sY;
  int q = t & 7, hr = t >> 3;  // hr 0..63
#pragma unroll
  for (int hb = 0; hb < 2; ++hb) {
    int h = hr + hb * 64;  // 0..127; mirror h+128 via se-so
    float se0r = 0, se0i = 0, se1r = 0, se1i = 0;
    float so0r = 0, so0i = 0, so1r = 0, so1i = 0;
#pragma unroll 4
    for (int kh2 = 0; kh2 < 16; ++kh2) {
      int khe = 2 * kh2, kho = khe + 1;
      int khae = khe < 16 ? khe : khe + 224;
      int khao = kho < 16 ? kho : kho + 224;
      float2 ee = sU[(khae * h) & 255];
      float2 eo = sU[(khao * h) & 255];
      float4 yE = sY4[khe * 8 + q];
      float4 yO = sY4[kho * 8 + q];
      se0r += yE.x * ee.x - yE.y * ee.y;
      se0i += yE.x * ee.y + yE.y * ee.x;
      se1r += yE.z * ee.x - yE.w * ee.y;
      se1i += yE.z * ee.y + yE.w * ee.x;
      so0r += yO.x * eo.x - yO.y * eo.y;
      so0i += yO.x * eo.y + yO.y * eo.x;
      so1r += yO.z * eo.x - yO.w * eo.y;
      so1i += yO.z * eo.y + yO.w * eo.x;
    }
    float* g0 = G + (((size_t)b * 256 + h) * 32 + o) * 32 + 4 * q;
    float* g1 = G + (((size_t)b * 256 + h + 128) * 32 + o) * 32 + 4 * q;
    *(float4*)g0 =
        make_float4(se0r + so0r, se0i + so0i, se1r + so1r, se1i + so1i);
    *(float4*)g1 =
        make_float4(se0r - so0r, se0i - so0i, se1r - so1r, se1i - so1i);
  }
}

// ------------------------------------------------- K5: w-IDFT (c2r) G -> out
// E4 generated inline (TRANS) in the G-load shadow; staged in LDS (16 KB).
__global__ __launch_bounds__(256) void k_widft(const float* __restrict__ G,
                                               float* __restrict__ out) {
  __shared__ float sG[32 * 33];
  __shared__ __align__(16) float4 sE4[1024];  // [w<128][q] 16 KB
  int bh = blockIdx.x, t = threadIdx.x;
  float4 v = ((const float4*)(G + (size_t)bh * 1024))[t];
#pragma unroll
  for (int r = 0; r < 4; ++r) {  // twiddle gen hidden under the G load
    int i = t + 256 * r;
    int w = i >> 3, q = i & 7;
    int me = (2 * q * w) & 255, mo = ((2 * q + 1) * w) & 255;
    float se, ce, so, co;
    sincosf(STEP256 * (float)me, &se, &ce);
    sincosf(STEP256 * (float)mo, &so, &co);
    float sc_e = (q == 0) ? INV_HW : 2.0f * INV_HW;
    sE4[i] = make_float4(sc_e * ce, sc_e * se, 2.0f * INV_HW * co,
                         2.0f * INV_HW * so);
  }
  {
    int o = t >> 3, p = t & 7;
    float* d = sG + o * 33 + p * 4;
    d[0] = v.x; d[1] = v.y; d[2] = v.z; d[3] = v.w;
  }
  __syncthreads();
  int o = t & 31, wb = t >> 5;
  float g[32];
#pragma unroll
  for (int k = 0; k < 32; ++k) g[k] = sG[o * 33 + k];
  float* ob = out + (size_t)bh * 8192 + o;
#pragma unroll 2
  for (int j = 0; j < 16; ++j) {
    int w = wb * 16 + j;
    float se = 0.f, so = 0.f;
#pragma unroll
    for (int q = 0; q < 8; ++q) {
      float4 e = sE4[w * 8 + q];
      se += g[4 * q] * e.x - g[4 * q + 1] * e.y;
      so += g[4 * q + 2] * e.z - g[4 * q + 3] * e.w;
    }
    ob[(size_t)w * 32] = se + so;
    ob[(size_t)(w + 128) * 32] = se - so;
  }
}

extern "C" void kernel_launch(void* const* d_in, const int* in_sizes, int n_in,
                              void* d_out, int out_size, void* d_ws,
                              size_t ws_size, hipStream_t stream) {
  const float* x = (const float*)d_in[0];   // [8,256,256,32]
  const float* wr = (const float*)d_in[1];  // [2,32,32,16,16]
  const float* wi = (const float*)d_in[2];
  float* out = (float*)d_out;               // [8,256,256,32]
  float* ws = (float*)d_ws;

  float* T = ws;            // 2097152 f  [b][c][h][kw][2]
  float* X = ws + 2097152;  // 262144 f   [b*32+c][row][kw][2]
  float* G = T;             // reuse (T dead after K2)

  k_wdft<<<1024, 512, 0, stream>>>(x, T);
  k_hdft<<<256, 1024, 0, stream>>>(T, X);
  k_mixidft<<<256, 512, 0, stream>>>(X, wr, wi, G);
  k_widft<<<2048, 256, 0, stream>>>(G, out);
}